// Round 6
// baseline (386.360 us; speedup 1.0000x reference)
//
#include <hip/hip_runtime.h>
#include <hip/hip_bf16.h>
#include <stdint.h>
#include <stddef.h>

// MultiHeadAttention: N=4, L=2048, E=1024, H=16, D=64, OUT=1024.
// fp32 in/out (per reference). bf16 MFMA internally, fp32 accumulate.
// Softmax scale 1/32 and log2(e) folded into Q: exp(s) == exp2(s_folded).

typedef __attribute__((ext_vector_type(8))) short bf16x8;   // 8 bf16 (4 VGPRs)
typedef __attribute__((ext_vector_type(4))) float f32x4;    // 4 fp32
typedef __attribute__((ext_vector_type(4))) short short4v;
typedef __attribute__((ext_vector_type(2))) uint32_t uint2v;

__device__ __forceinline__ f32x4 mfma16(bf16x8 a, bf16x8 b, f32x4 c) {
    return __builtin_amdgcn_mfma_f32_16x16x32_bf16(a, b, c, 0, 0, 0);
}

__device__ __forceinline__ short f2bf(float x) {
    union { float f; uint32_t u; } v; v.f = x;
    uint32_t r = (v.u + 0x7FFFu + ((v.u >> 16) & 1u)) >> 16;
    return (short)(uint16_t)r;
}

// pack 2 fp32 -> 2 bf16 in one dword (v_cvt_pk path)
__device__ __forceinline__ uint32_t pk2bf(float a, float b) {
    union { __hip_bfloat162 h; uint32_t u; } v;
    v.h = __float22bfloat162_rn(float2{a, b});
    return v.u;
}

// load 8 consecutive fp32, round-to-nearest-even to bf16x8
__device__ __forceinline__ bf16x8 cvt8(const float* __restrict__ p) {
    f32x4 a = *(const f32x4*)p;
    f32x4 b = *(const f32x4*)(p + 4);
    bf16x8 r;
    r[0] = f2bf(a[0]); r[1] = f2bf(a[1]); r[2] = f2bf(a[2]); r[3] = f2bf(a[3]);
    r[4] = f2bf(b[0]); r[5] = f2bf(b[1]); r[6] = f2bf(b[2]); r[7] = f2bf(b[3]);
    return r;
}

// ---------------------------------------------------------------------------
// Kernel 1: K/V projection.  grid = 64 nh * 16 ltiles = 1024, block = 256.
// K_ws layout [nh][l][d] (bf16);
// V_ws layout tile-blocked V^T: [nh][kt=l/64][d=64][l%64] (bf16).
// ---------------------------------------------------------------------------
__global__ __launch_bounds__(256)
void kvproj_kernel(const float* __restrict__ x, const float* __restrict__ Wk,
                   const float* __restrict__ Wv, short* __restrict__ k_ws,
                   short* __restrict__ v_ws) {
    __shared__ alignas(16) short xt[128 * 72];
    int tid = threadIdx.x;
    int lt = blockIdx.x & 15, nh = blockIdx.x >> 4;
    int n = nh >> 4, h = nh & 15;
    int l0 = lt * 128;
    int wv = tid >> 6, lane = tid & 63, quad = lane >> 4, lc = lane & 15;

    for (int u = tid; u < 1024; u += 256) {
        int r = u >> 3, c = (u & 7) * 8;
        *(bf16x8*)(xt + r * 72 + c) =
            cvt8(x + (size_t)(n * 2048 + l0 + r) * 1024 + h * 64 + c);
    }
    __syncthreads();

    bf16x8 xa[2][2];
    for (int mt = 0; mt < 2; ++mt)
        for (int kf = 0; kf < 2; ++kf)
            xa[mt][kf] = *(bf16x8*)(xt + (wv * 32 + mt * 16 + lc) * 72 + kf * 32 + quad * 8);

    f32x4 ka[2][4] = {}, va[2][4] = {};
    for (int nt = 0; nt < 4; ++nt)
        for (int kf = 0; kf < 2; ++kf) {
            bf16x8 wkb = cvt8(Wk + (nt * 16 + lc) * 64 + kf * 32 + quad * 8);
            bf16x8 wvb = cvt8(Wv + (nt * 16 + lc) * 64 + kf * 32 + quad * 8);
            for (int mt = 0; mt < 2; ++mt) {
                ka[mt][nt] = mfma16(xa[mt][kf], wkb, ka[mt][nt]);
                va[mt][nt] = mfma16(xa[mt][kf], wvb, va[mt][nt]);
            }
        }

    for (int mt = 0; mt < 2; ++mt) {
        int off = wv * 32 + mt * 16;            // 0..112
        int ktile = (l0 + off) >> 6;            // global 64-key tile index
        int lo = ((l0 + off) & 63) + quad * 4;  // offset within tile
        for (int nt = 0; nt < 4; ++nt) {
            for (int i = 0; i < 4; ++i)
                k_ws[((size_t)nh * 2048 + l0 + off + quad * 4 + i) * 64 +
                     nt * 16 + lc] = f2bf(ka[mt][nt][i]);
            short4v pk;
            for (int i = 0; i < 4; ++i) pk[i] = f2bf(va[mt][nt][i]);
            *(short4v*)(v_ws + (size_t)nh * 131072 + (size_t)ktile * 4096 +
                        (nt * 16 + lc) * 64 + lo) = pk;
        }
    }
}

// ---------------------------------------------------------------------------
// Kernel 2: fused Q-projection + flash attention, transposed-S formulation.
// grid: blockIdx = qt*64 + nh  (same-nh blocks share an XCD: b%8 == nh%8).
// block = 256 (4 waves x 32 q-rows).  LDS: only pbuf 128x72 (18 KB) =
// X/Q staging, then P^T [q-row][key0..63].  Main loop has NO barriers:
// K/V A-frags load straight from global to registers; P^T rows are
// wave-private (write b64 / read b128 only).
// S^T = mfma(K_frag, q_frag)  (q A-frag bytes double as B-frag of Q^T);
// O^T = mfma(V^T_frag, P^T_frag).
// ---------------------------------------------------------------------------
__global__ __launch_bounds__(256)
void flash_kernel(const float* __restrict__ x, const float* __restrict__ Wq,
                  const short* __restrict__ k_ws, const short* __restrict__ v_ws,
                  short* __restrict__ ao) {
    __shared__ alignas(16) short pbuf[128 * 72];  // 18 KB
    int tid = threadIdx.x;
    int nh = blockIdx.x & 63, qt = blockIdx.x >> 6;
    int n = nh >> 4, h = nh & 15;
    int q0 = qt * 128;
    int wv = tid >> 6, lane = tid & 63, quad = lane >> 4, lc = lane & 15;

    // ---- fused Q projection (X staged in pbuf) ----
    for (int u = tid; u < 1024; u += 256) {
        int r = u >> 3, c = (u & 7) * 8;
        *(bf16x8*)(pbuf + r * 72 + c) =
            cvt8(x + (size_t)(n * 2048 + q0 + r) * 1024 + h * 64 + c);
    }
    __syncthreads();
    bf16x8 xa[2][2];
    for (int mt = 0; mt < 2; ++mt)
        for (int kf = 0; kf < 2; ++kf)
            xa[mt][kf] = *(bf16x8*)(pbuf + (wv * 32 + mt * 16 + lc) * 72 + kf * 32 + quad * 8);
    f32x4 qacc[2][4] = {};
    for (int nt = 0; nt < 4; ++nt)
        for (int kf = 0; kf < 2; ++kf) {
            bf16x8 wb = cvt8(Wq + (nt * 16 + lc) * 64 + kf * 32 + quad * 8);
            for (int mt = 0; mt < 2; ++mt) qacc[mt][nt] = mfma16(xa[mt][kf], wb, qacc[mt][nt]);
        }
    // write scaled Q to own rows, read back as A-frag (wave-private, no barrier)
    const float QS = 0.04508422002778011f;  // log2(e) / sqrt(1024)
    for (int mt = 0; mt < 2; ++mt)
        for (int nt = 0; nt < 4; ++nt)
            for (int i = 0; i < 4; ++i)
                pbuf[(wv * 32 + mt * 16 + quad * 4 + i) * 72 + nt * 16 + lc] =
                    f2bf(qacc[mt][nt][i] * QS);
    bf16x8 qa[2][2];
    for (int mt = 0; mt < 2; ++mt)
        for (int kf = 0; kf < 2; ++kf)
            qa[mt][kf] = *(bf16x8*)(pbuf + (wv * 32 + mt * 16 + lc) * 72 + kf * 32 + quad * 8);

    f32x4 o[2][4] = {};     // o[q2][dt]: O^T[d=dt*16+quad*4+i][q=q2*16+lc]
    float lsum[2] = {0.f, 0.f};
    const short* kbase = k_ws + (size_t)nh * 2048 * 64;
    const short* vbase = v_ws + (size_t)nh * 131072;
    int fragoff = lc * 64 + quad * 8;  // shared by K and V A-frag addressing

    for (int kt = 0; kt < 32; ++kt) {
        const short* kp = kbase + (size_t)kt * 4096 + fragoff;
        const short* vp = vbase + (size_t)kt * 4096 + fragoff;
        // K A-frags: A[m=key=t*16+lc][k=d=kf*32+quad*8+j]
        bf16x8 kA[4][2];
#pragma unroll
        for (int t = 0; t < 4; ++t)
            for (int kf = 0; kf < 2; ++kf)
                kA[t][kf] = *(const bf16x8*)(kp + t * 1024 + kf * 32);
        // S^T = K · Q^T : C[m=key][n=q]
        f32x4 s[2][4] = {};
#pragma unroll
        for (int t = 0; t < 4; ++t)
            for (int q2 = 0; q2 < 2; ++q2) {
                s[q2][t] = mfma16(kA[t][0], qa[q2][0], s[q2][t]);
                s[q2][t] = mfma16(kA[t][1], qa[q2][1], s[q2][t]);
            }
        // V^T A-frags: A[m=d=dt*16+lc][k=key=kf*32+quad*8+j]
        bf16x8 vA[4][2];
#pragma unroll
        for (int dt = 0; dt < 4; ++dt)
            for (int kf = 0; kf < 2; ++kf)
                vA[dt][kf] = *(const bf16x8*)(vp + dt * 1024 + kf * 32);
        // exp2, per-lane lsum partials, pack, store P^T (wave-private rows)
#pragma unroll
        for (int q2 = 0; q2 < 2; ++q2) {
            int prow = (wv * 32 + q2 * 16 + lc) * 72;
            float ts = 0.f;
#pragma unroll
            for (int t = 0; t < 4; ++t) {
                float p0 = __builtin_amdgcn_exp2f(s[q2][t][0]);
                float p1 = __builtin_amdgcn_exp2f(s[q2][t][1]);
                float p2 = __builtin_amdgcn_exp2f(s[q2][t][2]);
                float p3 = __builtin_amdgcn_exp2f(s[q2][t][3]);
                ts += (p0 + p1) + (p2 + p3);
                uint2v w = {pk2bf(p0, p1), pk2bf(p2, p3)};
                *(uint2v*)(pbuf + prow + t * 16 + quad * 4) = w;
            }
            lsum[q2] += ts;
        }
        // O^T += V^T · P^T
#pragma unroll
        for (int q2 = 0; q2 < 2; ++q2)
            for (int kf = 0; kf < 2; ++kf) {
                bf16x8 pB = *(bf16x8*)(pbuf + (wv * 32 + q2 * 16 + lc) * 72 +
                                       kf * 32 + quad * 8);
                for (int dt = 0; dt < 4; ++dt)
                    o[q2][dt] = mfma16(vA[dt][kf], pB, o[q2][dt]);
            }
    }

    // epilogue: reduce lsum across quads (lanes sharing lc), normalize, store
    for (int q2 = 0; q2 < 2; ++q2) {
        float t = lsum[q2];
        t += __shfl_xor(t, 16, 64);
        t += __shfl_xor(t, 32, 64);
        float inv = 1.f / t;
        int q = q0 + wv * 32 + q2 * 16 + lc;
        for (int dt = 0; dt < 4; ++dt) {
            short4v pk;
            for (int i = 0; i < 4; ++i) pk[i] = f2bf(o[q2][dt][i] * inv);
            *(short4v*)(ao + (size_t)(n * 2048 + q) * 1024 + h * 64 +
                        dt * 16 + quad * 4) = pk;
        }
    }
}

// ---------------------------------------------------------------------------
// Kernel 3: out = AO @ Wo^T + bo.  M=8192, N=1024, K=1024. AO bf16, Wo/bo/out fp32.
// 128x128 tile, BK=32, 4 waves in 2x2 -> 64x64 each.
// ---------------------------------------------------------------------------
__global__ __launch_bounds__(256)
void outgemm_kernel(const short* __restrict__ A, const float* __restrict__ Wo,
                    const float* __restrict__ bo, float* __restrict__ out) {
    __shared__ alignas(16) short at[128 * 40];
    __shared__ alignas(16) short bt[128 * 40];
    int tid = threadIdx.x;
    int bm = blockIdx.x >> 3, bn = blockIdx.x & 7;
    int m0 = bm * 128, n0 = bn * 128;
    int wv = tid >> 6, lane = tid & 63, quad = lane >> 4, lc = lane & 15;
    int wr = wv >> 1, wc = wv & 1;

    int r1 = tid >> 2, c1 = (tid & 3) * 8;
    int u2 = tid + 256;
    int r2 = u2 >> 2, c2 = (u2 & 3) * 8;

    f32x4 acc[4][4] = {};
    for (int kt = 0; kt < 32; ++kt) {
        int k0 = kt * 32;
        bf16x8 a0 = *(const bf16x8*)(A + (size_t)(m0 + r1) * 1024 + k0 + c1);
        bf16x8 a1 = *(const bf16x8*)(A + (size_t)(m0 + r2) * 1024 + k0 + c2);
        bf16x8 b0 = cvt8(Wo + (size_t)(n0 + r1) * 1024 + k0 + c1);
        bf16x8 b1 = cvt8(Wo + (size_t)(n0 + r2) * 1024 + k0 + c2);
        __syncthreads();
        *(bf16x8*)(at + r1 * 40 + c1) = a0;
        *(bf16x8*)(at + r2 * 40 + c2) = a1;
        *(bf16x8*)(bt + r1 * 40 + c1) = b0;
        *(bf16x8*)(bt + r2 * 40 + c2) = b1;
        __syncthreads();
        bf16x8 af[4], bfr[4];
        for (int mt = 0; mt < 4; ++mt)
            af[mt] = *(bf16x8*)(at + (wr * 64 + mt * 16 + lc) * 40 + quad * 8);
        for (int nt = 0; nt < 4; ++nt)
            bfr[nt] = *(bf16x8*)(bt + (wc * 64 + nt * 16 + lc) * 40 + quad * 8);
        for (int mt = 0; mt < 4; ++mt)
            for (int nt = 0; nt < 4; ++nt)
                acc[mt][nt] = mfma16(af[mt], bfr[nt], acc[mt][nt]);
    }
    for (int nt = 0; nt < 4; ++nt) {
        float bv = bo[n0 + wc * 64 + nt * 16 + lc];
        for (int mt = 0; mt < 4; ++mt)
            for (int i = 0; i < 4; ++i) {
                int m = m0 + wr * 64 + mt * 16 + quad * 4 + i;
                int nn = n0 + wc * 64 + nt * 16 + lc;
                out[(size_t)m * 1024 + nn] = acc[mt][nt][i] + bv;
            }
    }
}

extern "C" void kernel_launch(void* const* d_in, const int* in_sizes, int n_in,
                              void* d_out, int out_size, void* d_ws, size_t ws_size,
                              hipStream_t stream) {
    const float* x  = (const float*)d_in[0];
    const float* Wq = (const float*)d_in[1];
    const float* Wk = (const float*)d_in[2];
    const float* Wv = (const float*)d_in[3];
    const float* Wo = (const float*)d_in[4];
    const float* bo = (const float*)d_in[5];
    float* out = (float*)d_out;

    short* k_ws  = (short*)d_ws;          // [64][2048][64] bf16  (16 MB)
    short* v_ws  = k_ws + 8388608;        // [64][32][64][64] bf16 tile-blocked V^T (16 MB)
    short* ao_ws = v_ws + 8388608;        // [4][2048][1024] bf16 (16 MB)

    kvproj_kernel<<<dim3(1024), dim3(256), 0, stream>>>(x, Wk, Wv, k_ws, v_ws);
    flash_kernel<<<dim3(1024), dim3(256), 0, stream>>>(x, Wq, k_ws, v_ws, ao_ws);
    outgemm_kernel<<<dim3(512), dim3(256), 0, stream>>>(ao_ws, Wo, bo, out);
}

// Round 7
// 234.431 us; speedup vs baseline: 1.6481x; 1.6481x over previous
//
#include <hip/hip_runtime.h>
#include <hip/hip_bf16.h>
#include <stdint.h>
#include <stddef.h>

// MultiHeadAttention: N=4, L=2048, E=1024, H=16, D=64, OUT=1024.
// fp32 in/out. bf16 MFMA internally, fp32 accumulate.
// K/V workspaces are stored FRAG-BLOCKED so flash loads fragments with
// lane-contiguous (coalesced) global reads: no LDS staging, no loop barriers.

typedef __attribute__((ext_vector_type(8))) short bf16x8;   // 8 bf16 (4 VGPRs)
typedef __attribute__((ext_vector_type(4))) float f32x4;    // 4 fp32
typedef __attribute__((ext_vector_type(4))) short short4v;
typedef __attribute__((ext_vector_type(2))) uint32_t uint2v;

__device__ __forceinline__ f32x4 mfma16(bf16x8 a, bf16x8 b, f32x4 c) {
    return __builtin_amdgcn_mfma_f32_16x16x32_bf16(a, b, c, 0, 0, 0);
}

__device__ __forceinline__ short f2bf(float x) {
    union { float f; uint32_t u; } v; v.f = x;
    uint32_t r = (v.u + 0x7FFFu + ((v.u >> 16) & 1u)) >> 16;
    return (short)(uint16_t)r;
}

__device__ __forceinline__ uint32_t pk2bf(float a, float b) {
    union { __hip_bfloat162 h; uint32_t u; } v;
    v.h = __float22bfloat162_rn(float2{a, b});
    return v.u;
}

__device__ __forceinline__ bf16x8 cvt8(const float* __restrict__ p) {
    f32x4 a = *(const f32x4*)p;
    f32x4 b = *(const f32x4*)(p + 4);
    bf16x8 r;
    r[0] = f2bf(a[0]); r[1] = f2bf(a[1]); r[2] = f2bf(a[2]); r[3] = f2bf(a[3]);
    r[4] = f2bf(b[0]); r[5] = f2bf(b[1]); r[6] = f2bf(b[2]); r[7] = f2bf(b[3]);
    return r;
}

// ---------------------------------------------------------------------------
// Kernel 1: K/V projection -> frag-blocked workspaces.
// grid = 64 nh * 16 ltiles = 1024, block = 256 (covers 2 key-tiles of 64).
// kf_ws[nh][kt][seg=t*2+kf][lane][8]: K[key=kt*64+t*16+(lane&15)]
//                                      [d=kf*32+(lane>>4)*8+j]
// vf_ws[nh][kt][seg=dt*2+kf][lane][8]: V[key=kt*64+kf*32+(lane>>4)*8+j]
//                                      [d=dt*16+(lane&15)]
// ---------------------------------------------------------------------------
__global__ __launch_bounds__(256)
void kvproj_kernel(const float* __restrict__ x, const float* __restrict__ Wk,
                   const float* __restrict__ Wv, short* __restrict__ kf_ws,
                   short* __restrict__ vf_ws) {
    __shared__ alignas(16) short kbuf[128 * 72];   // X stage, then K[key][d]
    __shared__ alignas(16) short vbuf[64 * 136];   // V^T[d][key 0..127]
    int tid = threadIdx.x;
    int lt = blockIdx.x & 15, nh = blockIdx.x >> 4;
    int n = nh >> 4, h = nh & 15;
    int l0 = lt * 128, kt0 = lt * 2;
    int wv = tid >> 6, lane = tid & 63, quad = lane >> 4, lc = lane & 15;

    for (int u = tid; u < 1024; u += 256) {
        int r = u >> 3, c = (u & 7) * 8;
        *(bf16x8*)(kbuf + r * 72 + c) =
            cvt8(x + (size_t)(n * 2048 + l0 + r) * 1024 + h * 64 + c);
    }
    __syncthreads();

    bf16x8 xa[2][2];
    for (int mt = 0; mt < 2; ++mt)
        for (int kf = 0; kf < 2; ++kf)
            xa[mt][kf] = *(bf16x8*)(kbuf + (wv * 32 + mt * 16 + lc) * 72 + kf * 32 + quad * 8);

    f32x4 ka[2][4] = {}, va[2][4] = {};
    for (int nt = 0; nt < 4; ++nt)
        for (int kf = 0; kf < 2; ++kf) {
            bf16x8 wkb = cvt8(Wk + (nt * 16 + lc) * 64 + kf * 32 + quad * 8);
            bf16x8 wvb = cvt8(Wv + (nt * 16 + lc) * 64 + kf * 32 + quad * 8);
            for (int mt = 0; mt < 2; ++mt) {
                ka[mt][nt] = mfma16(xa[mt][kf], wkb, ka[mt][nt]);
                va[mt][nt] = mfma16(xa[mt][kf], wvb, va[mt][nt]);
            }
        }

    // scatter into LDS staging (wave-private rows for kbuf; vbuf by column)
    for (int mt = 0; mt < 2; ++mt) {
        int off = wv * 32 + mt * 16;  // key base within 128
        for (int nt = 0; nt < 4; ++nt)
            for (int i = 0; i < 4; ++i) {
                float kv = ka[mt][nt][i], vv = va[mt][nt][i];
                kbuf[(off + quad * 4 + i) * 72 + nt * 16 + lc] = f2bf(kv);
                vbuf[(nt * 16 + lc) * 136 + off + quad * 4 + i] = f2bf(vv);
            }
    }
    __syncthreads();

    // coalesced frag-blocked stores (lane*16B contiguous)
    size_t base = (size_t)nh * 131072 + (size_t)kt0 * 4096;
    for (int u = tid; u < 1024; u += 256) {
        int tile = u >> 9, rem = u & 511, seg = rem >> 6, ln = u & 63;
        int t = seg >> 1, kf = seg & 1;
        int lq = ln >> 4, ll = ln & 15;
        bf16x8 kw = *(bf16x8*)(kbuf + (tile * 64 + t * 16 + ll) * 72 + kf * 32 + lq * 8);
        *(bf16x8*)(kf_ws + base + (size_t)tile * 4096 + seg * 512 + ln * 8) = kw;
        bf16x8 vw = *(bf16x8*)(vbuf + (t * 16 + ll) * 136 + tile * 64 + kf * 32 + lq * 8);
        *(bf16x8*)(vf_ws + base + (size_t)tile * 4096 + seg * 512 + ln * 8) = vw;
    }
}

// ---------------------------------------------------------------------------
// Kernel 2: fused Q-projection + flash attention, transposed-S formulation.
// grid: blockIdx = qt*64 + nh (b%8 == nh%8 -> same-nh blocks share an XCD).
// block = 256 = 4 waves x 64 q-rows (256-q tile), 8 q-tiles -> grid 512.
// LDS: only pbuf 256x72 (36 KB) = X/Q staging, then P^T (wave-private rows).
// Main loop: NO barriers; K/V frags via coalesced global loads.
// ---------------------------------------------------------------------------
__global__ __launch_bounds__(256, 2)
void flash_kernel(const float* __restrict__ x, const float* __restrict__ Wq,
                  const short* __restrict__ kf_ws, const short* __restrict__ vf_ws,
                  short* __restrict__ ao) {
    __shared__ alignas(16) short pbuf[256 * 72];  // 36 KB
    int tid = threadIdx.x;
    int nh = blockIdx.x & 63, qt = blockIdx.x >> 6;
    int n = nh >> 4, h = nh & 15;
    int q0 = qt * 256;
    int wv = tid >> 6, lane = tid & 63, quad = lane >> 4, lc = lane & 15;

    // ---- fused Q projection: stage X (256 rows), project own 64 rows ----
    for (int u = tid; u < 2048; u += 256) {
        int r = u >> 3, c = (u & 7) * 8;
        *(bf16x8*)(pbuf + r * 72 + c) =
            cvt8(x + (size_t)(n * 2048 + q0 + r) * 1024 + h * 64 + c);
    }
    __syncthreads();
    {
        bf16x8 xa[4][2];
        for (int mt = 0; mt < 4; ++mt)
            for (int kf = 0; kf < 2; ++kf)
                xa[mt][kf] = *(bf16x8*)(pbuf + (wv * 64 + mt * 16 + lc) * 72 +
                                        kf * 32 + quad * 8);
        f32x4 qacc[4][4] = {};
        for (int nt = 0; nt < 4; ++nt)
            for (int kf = 0; kf < 2; ++kf) {
                bf16x8 wb = cvt8(Wq + (nt * 16 + lc) * 64 + kf * 32 + quad * 8);
                for (int mt = 0; mt < 4; ++mt)
                    qacc[mt][nt] = mfma16(xa[mt][kf], wb, qacc[mt][nt]);
            }
        const float QS = 0.04508422002778011f;  // log2(e) / sqrt(1024)
        for (int mt = 0; mt < 4; ++mt)
            for (int nt = 0; nt < 4; ++nt)
                for (int i = 0; i < 4; ++i)
                    pbuf[(wv * 64 + mt * 16 + quad * 4 + i) * 72 + nt * 16 + lc] =
                        f2bf(qacc[mt][nt][i] * QS);
    }
    bf16x8 qa[4][2];
    for (int mt = 0; mt < 4; ++mt)
        for (int kf = 0; kf < 2; ++kf)
            qa[mt][kf] = *(bf16x8*)(pbuf + (wv * 64 + mt * 16 + lc) * 72 +
                                    kf * 32 + quad * 8);

    f32x4 o[4][4] = {};        // o[q2][dt]: O^T[d=dt*16+quad*4+i][q=q2*16+lc]
    float lsum[4] = {0.f, 0.f, 0.f, 0.f};
    const short* kbase = kf_ws + (size_t)nh * 131072 + lane * 8;
    const short* vbase = vf_ws + (size_t)nh * 131072 + lane * 8;

    for (int kt = 0; kt < 32; ++kt) {
        const short* kp = kbase + (size_t)kt * 4096;
        const short* vp = vbase + (size_t)kt * 4096;
        // K A-frags: coalesced (lane*16B)
        bf16x8 kA[4][2];
#pragma unroll
        for (int t = 0; t < 4; ++t)
            for (int kf = 0; kf < 2; ++kf)
                kA[t][kf] = *(const bf16x8*)(kp + (t * 2 + kf) * 512);
        // S^T = K · Q^T
        f32x4 s[4][4] = {};
#pragma unroll
        for (int t = 0; t < 4; ++t)
            for (int q2 = 0; q2 < 4; ++q2) {
                s[q2][t] = mfma16(kA[t][0], qa[q2][0], s[q2][t]);
                s[q2][t] = mfma16(kA[t][1], qa[q2][1], s[q2][t]);
            }
        // V^T A-frags
        bf16x8 vA[4][2];
#pragma unroll
        for (int dt = 0; dt < 4; ++dt)
            for (int kf = 0; kf < 2; ++kf)
                vA[dt][kf] = *(const bf16x8*)(vp + (dt * 2 + kf) * 512);
        // exp2, lsum partials, pack+store P^T (wave-private rows)
#pragma unroll
        for (int q2 = 0; q2 < 4; ++q2) {
            int prow = (wv * 64 + q2 * 16 + lc) * 72;
            float ts = 0.f;
#pragma unroll
            for (int t = 0; t < 4; ++t) {
                float p0 = __builtin_amdgcn_exp2f(s[q2][t][0]);
                float p1 = __builtin_amdgcn_exp2f(s[q2][t][1]);
                float p2 = __builtin_amdgcn_exp2f(s[q2][t][2]);
                float p3 = __builtin_amdgcn_exp2f(s[q2][t][3]);
                ts += (p0 + p1) + (p2 + p3);
                uint2v w = {pk2bf(p0, p1), pk2bf(p2, p3)};
                *(uint2v*)(pbuf + prow + t * 16 + quad * 4) = w;
            }
            lsum[q2] += ts;
        }
        // O^T += V^T · P^T
#pragma unroll
        for (int q2 = 0; q2 < 4; ++q2)
            for (int kf = 0; kf < 2; ++kf) {
                bf16x8 pB = *(bf16x8*)(pbuf + (wv * 64 + q2 * 16 + lc) * 72 +
                                       kf * 32 + quad * 8);
                for (int dt = 0; dt < 4; ++dt)
                    o[q2][dt] = mfma16(vA[dt][kf], pB, o[q2][dt]);
            }
    }

    // epilogue: reduce lsum across quads, normalize, store O
    for (int q2 = 0; q2 < 4; ++q2) {
        float t = lsum[q2];
        t += __shfl_xor(t, 16, 64);
        t += __shfl_xor(t, 32, 64);
        float inv = 1.f / t;
        int q = q0 + wv * 64 + q2 * 16 + lc;
        for (int dt = 0; dt < 4; ++dt) {
            short4v pk;
            for (int i = 0; i < 4; ++i) pk[i] = f2bf(o[q2][dt][i] * inv);
            *(short4v*)(ao + (size_t)(n * 2048 + q) * 1024 + h * 64 +
                        dt * 16 + quad * 4) = pk;
        }
    }
}

// ---------------------------------------------------------------------------
// Kernel 3: out = AO @ Wo^T + bo.  M=8192, N=1024, K=1024. AO bf16, Wo/bo/out fp32.
// 128x128 tile, BK=32, 4 waves in 2x2 -> 64x64 each.
// ---------------------------------------------------------------------------
__global__ __launch_bounds__(256)
void outgemm_kernel(const short* __restrict__ A, const float* __restrict__ Wo,
                    const float* __restrict__ bo, float* __restrict__ out) {
    __shared__ alignas(16) short at[128 * 40];
    __shared__ alignas(16) short bt[128 * 40];
    int tid = threadIdx.x;
    int bm = blockIdx.x >> 3, bn = blockIdx.x & 7;
    int m0 = bm * 128, n0 = bn * 128;
    int wv = tid >> 6, lane = tid & 63, quad = lane >> 4, lc = lane & 15;
    int wr = wv >> 1, wc = wv & 1;

    int r1 = tid >> 2, c1 = (tid & 3) * 8;
    int u2 = tid + 256;
    int r2 = u2 >> 2, c2 = (u2 & 3) * 8;

    f32x4 acc[4][4] = {};
    for (int kt = 0; kt < 32; ++kt) {
        int k0 = kt * 32;
        bf16x8 a0 = *(const bf16x8*)(A + (size_t)(m0 + r1) * 1024 + k0 + c1);
        bf16x8 a1 = *(const bf16x8*)(A + (size_t)(m0 + r2) * 1024 + k0 + c2);
        bf16x8 b0 = cvt8(Wo + (size_t)(n0 + r1) * 1024 + k0 + c1);
        bf16x8 b1 = cvt8(Wo + (size_t)(n0 + r2) * 1024 + k0 + c2);
        __syncthreads();
        *(bf16x8*)(at + r1 * 40 + c1) = a0;
        *(bf16x8*)(at + r2 * 40 + c2) = a1;
        *(bf16x8*)(bt + r1 * 40 + c1) = b0;
        *(bf16x8*)(bt + r2 * 40 + c2) = b1;
        __syncthreads();
        bf16x8 af[4], bfr[4];
        for (int mt = 0; mt < 4; ++mt)
            af[mt] = *(bf16x8*)(at + (wr * 64 + mt * 16 + lc) * 40 + quad * 8);
        for (int nt = 0; nt < 4; ++nt)
            bfr[nt] = *(bf16x8*)(bt + (wc * 64 + nt * 16 + lc) * 40 + quad * 8);
        for (int mt = 0; mt < 4; ++mt)
            for (int nt = 0; nt < 4; ++nt)
                acc[mt][nt] = mfma16(af[mt], bfr[nt], acc[mt][nt]);
    }
    for (int nt = 0; nt < 4; ++nt) {
        float bv = bo[n0 + wc * 64 + nt * 16 + lc];
        for (int mt = 0; mt < 4; ++mt)
            for (int i = 0; i < 4; ++i) {
                int m = m0 + wr * 64 + mt * 16 + quad * 4 + i;
                int nn = n0 + wc * 64 + nt * 16 + lc;
                out[(size_t)m * 1024 + nn] = acc[mt][nt][i] + bv;
            }
    }
}

extern "C" void kernel_launch(void* const* d_in, const int* in_sizes, int n_in,
                              void* d_out, int out_size, void* d_ws, size_t ws_size,
                              hipStream_t stream) {
    const float* x  = (const float*)d_in[0];
    const float* Wq = (const float*)d_in[1];
    const float* Wk = (const float*)d_in[2];
    const float* Wv = (const float*)d_in[3];
    const float* Wo = (const float*)d_in[4];
    const float* bo = (const float*)d_in[5];
    float* out = (float*)d_out;

    short* kf_ws = (short*)d_ws;          // frag-blocked K (16 MB)
    short* vf_ws = kf_ws + 8388608;       // frag-blocked V^T (16 MB)
    short* ao_ws = vf_ws + 8388608;       // [4][2048][1024] bf16 (16 MB)

    kvproj_kernel<<<dim3(1024), dim3(256), 0, stream>>>(x, Wk, Wv, kf_ws, vf_ws);
    flash_kernel<<<dim3(512), dim3(256), 0, stream>>>(x, Wq, kf_ws, vf_ws, ao_ws);
    outgemm_kernel<<<dim3(512), dim3(256), 0, stream>>>(ao_ws, Wo, bo, out);
}

// Round 8
// 223.758 us; speedup vs baseline: 1.7267x; 1.0477x over previous
//
#include <hip/hip_runtime.h>
#include <hip/hip_bf16.h>
#include <stdint.h>
#include <stddef.h>

// MultiHeadAttention: N=4, L=2048, E=1024, H=16, D=64, OUT=1024.
// fp32 in/out. bf16 MFMA internally, fp32 accumulate.
// All hot GEMM loops stream MFMA fragments from FRAG-BLOCKED global buffers
// with lane-contiguous loads: no LDS staging, no barriers in main loops.

typedef __attribute__((ext_vector_type(8))) short bf16x8;   // 8 bf16 (4 VGPRs)
typedef __attribute__((ext_vector_type(4))) float f32x4;    // 4 fp32
typedef __attribute__((ext_vector_type(4))) short short4v;
typedef __attribute__((ext_vector_type(2))) uint32_t uint2v;

__device__ __forceinline__ f32x4 mfma16(bf16x8 a, bf16x8 b, f32x4 c) {
    return __builtin_amdgcn_mfma_f32_16x16x32_bf16(a, b, c, 0, 0, 0);
}

__device__ __forceinline__ short f2bf(float x) {
    union { float f; uint32_t u; } v; v.f = x;
    uint32_t r = (v.u + 0x7FFFu + ((v.u >> 16) & 1u)) >> 16;
    return (short)(uint16_t)r;
}

__device__ __forceinline__ uint32_t pk2bf(float a, float b) {
    union { __hip_bfloat162 h; uint32_t u; } v;
    v.h = __float22bfloat162_rn(float2{a, b});
    return v.u;
}

__device__ __forceinline__ bf16x8 cvt8(const float* __restrict__ p) {
    f32x4 a = *(const f32x4*)p;
    f32x4 b = *(const f32x4*)(p + 4);
    bf16x8 r;
    r[0] = f2bf(a[0]); r[1] = f2bf(a[1]); r[2] = f2bf(a[2]); r[3] = f2bf(a[3]);
    r[4] = f2bf(b[0]); r[5] = f2bf(b[1]); r[6] = f2bf(b[2]); r[7] = f2bf(b[3]);
    return r;
}

// ---------------------------------------------------------------------------
// Kernel 1: K/V projection -> frag-blocked workspaces.
// kf_ws[nh][kt][seg=t*2+kf][lane][8]: K[key=kt*64+t*16+(lane&15)][d=kf*32+(lane>>4)*8+j]
// vf_ws[nh][kt][seg=dt*2+kf][lane][8]: V[key=kt*64+kf*32+(lane>>4)*8+j][d=dt*16+(lane&15)]
// ---------------------------------------------------------------------------
__global__ __launch_bounds__(256)
void kvproj_kernel(const float* __restrict__ x, const float* __restrict__ Wk,
                   const float* __restrict__ Wv, short* __restrict__ kf_ws,
                   short* __restrict__ vf_ws) {
    __shared__ alignas(16) short kbuf[128 * 72];   // X stage, then K[key][d]
    __shared__ alignas(16) short vbuf[64 * 136];   // V^T[d][key 0..127]
    int tid = threadIdx.x;
    int lt = blockIdx.x & 15, nh = blockIdx.x >> 4;
    int n = nh >> 4, h = nh & 15;
    int l0 = lt * 128, kt0 = lt * 2;
    int wv = tid >> 6, lane = tid & 63, quad = lane >> 4, lc = lane & 15;

    for (int u = tid; u < 1024; u += 256) {
        int r = u >> 3, c = (u & 7) * 8;
        *(bf16x8*)(kbuf + r * 72 + c) =
            cvt8(x + (size_t)(n * 2048 + l0 + r) * 1024 + h * 64 + c);
    }
    __syncthreads();

    bf16x8 xa[2][2];
    for (int mt = 0; mt < 2; ++mt)
        for (int kf = 0; kf < 2; ++kf)
            xa[mt][kf] = *(bf16x8*)(kbuf + (wv * 32 + mt * 16 + lc) * 72 + kf * 32 + quad * 8);

    f32x4 ka[2][4] = {}, va[2][4] = {};
    for (int nt = 0; nt < 4; ++nt)
        for (int kf = 0; kf < 2; ++kf) {
            bf16x8 wkb = cvt8(Wk + (nt * 16 + lc) * 64 + kf * 32 + quad * 8);
            bf16x8 wvb = cvt8(Wv + (nt * 16 + lc) * 64 + kf * 32 + quad * 8);
            for (int mt = 0; mt < 2; ++mt) {
                ka[mt][nt] = mfma16(xa[mt][kf], wkb, ka[mt][nt]);
                va[mt][nt] = mfma16(xa[mt][kf], wvb, va[mt][nt]);
            }
        }

    for (int mt = 0; mt < 2; ++mt) {
        int off = wv * 32 + mt * 16;  // key base within 128
        for (int nt = 0; nt < 4; ++nt) {
            short4v pv;
            for (int i = 0; i < 4; ++i) {
                kbuf[(off + quad * 4 + i) * 72 + nt * 16 + lc] = f2bf(ka[mt][nt][i]);
                pv[i] = f2bf(va[mt][nt][i]);
            }
            *(short4v*)(vbuf + (nt * 16 + lc) * 136 + off + quad * 4) = pv;
        }
    }
    __syncthreads();

    // coalesced frag-blocked stores (lane*16B contiguous)
    size_t base = (size_t)nh * 131072 + (size_t)kt0 * 4096;
    for (int u = tid; u < 1024; u += 256) {
        int tile = u >> 9, rem = u & 511, seg = rem >> 6, ln = u & 63;
        int t = seg >> 1, kf = seg & 1;
        int lq = ln >> 4, ll = ln & 15;
        bf16x8 kw = *(bf16x8*)(kbuf + (tile * 64 + t * 16 + ll) * 72 + kf * 32 + lq * 8);
        *(bf16x8*)(kf_ws + base + (size_t)tile * 4096 + seg * 512 + ln * 8) = kw;
        bf16x8 vw = *(bf16x8*)(vbuf + (t * 16 + ll) * 136 + tile * 64 + kf * 32 + lq * 8);
        *(bf16x8*)(vf_ws + base + (size_t)tile * 4096 + seg * 512 + ln * 8) = vw;
    }
}

// ---------------------------------------------------------------------------
// Kernel 2: fused Q-projection + flash attention, transposed-S formulation.
// grid: blockIdx = qt*64 + nh (b%8 == nh%8 -> same-nh blocks share an XCD).
// block = 256 = 4 waves x 64 q-rows (256-q tile), grid 512.
// AO is written A-FRAG-BLOCKED: afb[mtile=row/16][kseg=k/32][lane][8] with
// element (row r, k) at ((mtile*32+kseg)*64 + ((k%32)/8)*16 + r%16)*8 + k%8.
// ---------------------------------------------------------------------------
__global__ __launch_bounds__(256, 2)
void flash_kernel(const float* __restrict__ x, const float* __restrict__ Wq,
                  const short* __restrict__ kf_ws, const short* __restrict__ vf_ws,
                  short* __restrict__ ao) {
    __shared__ alignas(16) short pbuf[256 * 72];  // 36 KB
    int tid = threadIdx.x;
    int nh = blockIdx.x & 63, qt = blockIdx.x >> 6;
    int n = nh >> 4, h = nh & 15;
    int q0 = qt * 256;
    int wv = tid >> 6, lane = tid & 63, quad = lane >> 4, lc = lane & 15;

    // ---- fused Q projection: stage X (256 rows), project own 64 rows ----
    for (int u = tid; u < 2048; u += 256) {
        int r = u >> 3, c = (u & 7) * 8;
        *(bf16x8*)(pbuf + r * 72 + c) =
            cvt8(x + (size_t)(n * 2048 + q0 + r) * 1024 + h * 64 + c);
    }
    __syncthreads();
    {
        bf16x8 xa[4][2];
        for (int mt = 0; mt < 4; ++mt)
            for (int kf = 0; kf < 2; ++kf)
                xa[mt][kf] = *(bf16x8*)(pbuf + (wv * 64 + mt * 16 + lc) * 72 +
                                        kf * 32 + quad * 8);
        f32x4 qacc[4][4] = {};
        for (int nt = 0; nt < 4; ++nt)
            for (int kf = 0; kf < 2; ++kf) {
                bf16x8 wb = cvt8(Wq + (nt * 16 + lc) * 64 + kf * 32 + quad * 8);
                for (int mt = 0; mt < 4; ++mt)
                    qacc[mt][nt] = mfma16(xa[mt][kf], wb, qacc[mt][nt]);
            }
        const float QS = 0.04508422002778011f;  // log2(e) / sqrt(1024)
        for (int mt = 0; mt < 4; ++mt)
            for (int nt = 0; nt < 4; ++nt)
                for (int i = 0; i < 4; ++i)
                    pbuf[(wv * 64 + mt * 16 + quad * 4 + i) * 72 + nt * 16 + lc] =
                        f2bf(qacc[mt][nt][i] * QS);
    }
    bf16x8 qa[4][2];
    for (int mt = 0; mt < 4; ++mt)
        for (int kf = 0; kf < 2; ++kf)
            qa[mt][kf] = *(bf16x8*)(pbuf + (wv * 64 + mt * 16 + lc) * 72 +
                                    kf * 32 + quad * 8);

    f32x4 o[4][4] = {};        // o[q2][dt]: O^T[d=dt*16+quad*4+i][q=q2*16+lc]
    float lsum[4] = {0.f, 0.f, 0.f, 0.f};
    const short* kbase = kf_ws + (size_t)nh * 131072 + lane * 8;
    const short* vbase = vf_ws + (size_t)nh * 131072 + lane * 8;

    for (int kt = 0; kt < 32; ++kt) {
        const short* kp = kbase + (size_t)kt * 4096;
        const short* vp = vbase + (size_t)kt * 4096;
        bf16x8 kA[4][2];
#pragma unroll
        for (int t = 0; t < 4; ++t)
            for (int kf = 0; kf < 2; ++kf)
                kA[t][kf] = *(const bf16x8*)(kp + (t * 2 + kf) * 512);
        f32x4 s[4][4] = {};
#pragma unroll
        for (int t = 0; t < 4; ++t)
            for (int q2 = 0; q2 < 4; ++q2) {
                s[q2][t] = mfma16(kA[t][0], qa[q2][0], s[q2][t]);
                s[q2][t] = mfma16(kA[t][1], qa[q2][1], s[q2][t]);
            }
        bf16x8 vA[4][2];
#pragma unroll
        for (int dt = 0; dt < 4; ++dt)
            for (int kf = 0; kf < 2; ++kf)
                vA[dt][kf] = *(const bf16x8*)(vp + (dt * 2 + kf) * 512);
#pragma unroll
        for (int q2 = 0; q2 < 4; ++q2) {
            int prow = (wv * 64 + q2 * 16 + lc) * 72;
            float ts = 0.f;
#pragma unroll
            for (int t = 0; t < 4; ++t) {
                float p0 = __builtin_amdgcn_exp2f(s[q2][t][0]);
                float p1 = __builtin_amdgcn_exp2f(s[q2][t][1]);
                float p2 = __builtin_amdgcn_exp2f(s[q2][t][2]);
                float p3 = __builtin_amdgcn_exp2f(s[q2][t][3]);
                ts += (p0 + p1) + (p2 + p3);
                uint2v w = {pk2bf(p0, p1), pk2bf(p2, p3)};
                *(uint2v*)(pbuf + prow + t * 16 + quad * 4) = w;
            }
            lsum[q2] += ts;
        }
#pragma unroll
        for (int q2 = 0; q2 < 4; ++q2)
            for (int kf = 0; kf < 2; ++kf) {
                bf16x8 pB = *(bf16x8*)(pbuf + (wv * 64 + q2 * 16 + lc) * 72 +
                                       kf * 32 + quad * 8);
                for (int dt = 0; dt < 4; ++dt)
                    o[q2][dt] = mfma16(vA[dt][kf], pB, o[q2][dt]);
            }
    }

    // epilogue: reduce lsum across quads, normalize, store AO frag-blocked
    for (int q2 = 0; q2 < 4; ++q2) {
        float t = lsum[q2];
        t += __shfl_xor(t, 16, 64);
        t += __shfl_xor(t, 32, 64);
        float inv = 1.f / t;
        int mtile = (n * 2048 + q0) / 16 + wv * 4 + q2;  // row = ..., r%16 = lc
        for (int dt = 0; dt < 4; ++dt) {
            // k = h*64 + dt*16 + quad*4 + i
            int kseg = h * 2 + (dt >> 1);
            int qd8 = ((dt & 1) * 4 + quad) >> 1;
            short4v pk;
            for (int i = 0; i < 4; ++i) pk[i] = f2bf(o[q2][dt][i] * inv);
            *(short4v*)(ao + (size_t)(mtile * 32 + kseg) * 512 +
                        (qd8 * 16 + lc) * 8 + (quad & 1) * 4) = pk;
        }
    }
}

// ---------------------------------------------------------------------------
// Kernel 3a: one-time Wo fp32 -> bf16 B-frag-blocked repack.
// wfb[ntile=n/16][kseg=k/32][lane=((k%32)/8)*16 + n%16][8 = k%8]
// grid 512, block 256: thread handles 8 consecutive k of one row n.
// ---------------------------------------------------------------------------
__global__ __launch_bounds__(256)
void wopack_kernel(const float* __restrict__ Wo, short* __restrict__ wfb) {
    int idx = blockIdx.x * 256 + threadIdx.x;   // 0..131071
    int nrow = idx >> 7;                        // 0..1023
    int k0 = (idx & 127) * 8;                   // 0..1016
    bf16x8 v = cvt8(Wo + (size_t)nrow * 1024 + k0);
    int ntile = nrow >> 4, lcn = nrow & 15;
    int kseg = k0 >> 5, qd = (k0 >> 3) & 3;
    *(bf16x8*)(wfb + ((size_t)(ntile * 32 + kseg) * 64 + qd * 16 + lcn) * 8) = v;
}

// ---------------------------------------------------------------------------
// Kernel 3b: out = AO @ Wo^T + bo.  M=8192, N=1024, K=1024.
// Pure register-streaming GEMM: A-frags from afb, B-frags from wfb, no LDS,
// no barriers.  grid: blockIdx = bn*64 + bm -> same-A (bm) blocks share XCD.
// 128x128 tile, 4 waves 2x2 -> 64x64 each; per kt: 8 loads + 16 MFMA.
// ---------------------------------------------------------------------------
__global__ __launch_bounds__(256)
void outgemm_kernel(const short* __restrict__ afb, const short* __restrict__ wfb,
                    const float* __restrict__ bo, float* __restrict__ out) {
    int tid = threadIdx.x;
    int bm = blockIdx.x & 63, bn = blockIdx.x >> 6;
    int m0 = bm * 128, n0 = bn * 128;
    int wv = tid >> 6, lane = tid & 63, quad = lane >> 4, lc = lane & 15;
    int wr = wv >> 1, wc = wv & 1;
    int mtb = bm * 8 + wr * 4;   // A row-tile base (16-row tiles)
    int ntb = bn * 8 + wc * 4;   // B col-tile base

    const short* ab = afb + lane * 8;
    const short* bb = wfb + lane * 8;

    f32x4 acc[4][4] = {};
    for (int kt = 0; kt < 32; ++kt) {
        bf16x8 af[4], bfr[4];
#pragma unroll
        for (int mt = 0; mt < 4; ++mt)
            af[mt] = *(const bf16x8*)(ab + ((size_t)(mtb + mt) * 32 + kt) * 512);
#pragma unroll
        for (int nt = 0; nt < 4; ++nt)
            bfr[nt] = *(const bf16x8*)(bb + ((size_t)(ntb + nt) * 32 + kt) * 512);
#pragma unroll
        for (int mt = 0; mt < 4; ++mt)
            for (int nt = 0; nt < 4; ++nt)
                acc[mt][nt] = mfma16(af[mt], bfr[nt], acc[mt][nt]);
    }
    for (int nt = 0; nt < 4; ++nt) {
        float bv = bo[n0 + wc * 64 + nt * 16 + lc];
        for (int mt = 0; mt < 4; ++mt)
            for (int i = 0; i < 4; ++i) {
                int m = m0 + wr * 64 + mt * 16 + quad * 4 + i;
                int nn = n0 + wc * 64 + nt * 16 + lc;
                out[(size_t)m * 1024 + nn] = acc[mt][nt][i] + bv;
            }
    }
}

extern "C" void kernel_launch(void* const* d_in, const int* in_sizes, int n_in,
                              void* d_out, int out_size, void* d_ws, size_t ws_size,
                              hipStream_t stream) {
    const float* x  = (const float*)d_in[0];
    const float* Wq = (const float*)d_in[1];
    const float* Wk = (const float*)d_in[2];
    const float* Wv = (const float*)d_in[3];
    const float* Wo = (const float*)d_in[4];
    const float* bo = (const float*)d_in[5];
    float* out = (float*)d_out;

    short* kf_ws = (short*)d_ws;          // frag-blocked K (16 MB); reused by wopack
    short* vf_ws = kf_ws + 8388608;       // frag-blocked V^T (16 MB)
    short* ao_ws = vf_ws + 8388608;       // frag-blocked AO (16 MB)
    short* wf_ws = kf_ws;                 // Wo frags (2 MB) — kf dead after flash

    kvproj_kernel<<<dim3(1024), dim3(256), 0, stream>>>(x, Wk, Wv, kf_ws, vf_ws);
    flash_kernel<<<dim3(512), dim3(256), 0, stream>>>(x, Wq, kf_ws, vf_ws, ao_ws);
    wopack_kernel<<<dim3(512), dim3(256), 0, stream>>>(Wo, wf_ws);
    outgemm_kernel<<<dim3(512), dim3(256), 0, stream>>>(ao_ws, wf_ws, bo, out);
}

// Round 9
// 222.773 us; speedup vs baseline: 1.7343x; 1.0044x over previous
//
#include <hip/hip_runtime.h>
#include <hip/hip_bf16.h>
#include <stdint.h>
#include <stddef.h>

// MultiHeadAttention: N=4, L=2048, E=1024, H=16, D=64, OUT=1024.
// fp32 in/out. bf16 MFMA internally, fp32 accumulate.
// All hot loops stream MFMA fragments from FRAG-BLOCKED global buffers with
// lane-contiguous loads: no LDS staging for K/V/W, no barriers in main loops.

typedef __attribute__((ext_vector_type(8))) short bf16x8;   // 8 bf16 (4 VGPRs)
typedef __attribute__((ext_vector_type(4))) float f32x4;    // 4 fp32
typedef __attribute__((ext_vector_type(4))) short short4v;
typedef __attribute__((ext_vector_type(2))) uint32_t uint2v;

__device__ __forceinline__ f32x4 mfma16(bf16x8 a, bf16x8 b, f32x4 c) {
    return __builtin_amdgcn_mfma_f32_16x16x32_bf16(a, b, c, 0, 0, 0);
}

__device__ __forceinline__ short f2bf(float x) {
    union { float f; uint32_t u; } v; v.f = x;
    uint32_t r = (v.u + 0x7FFFu + ((v.u >> 16) & 1u)) >> 16;
    return (short)(uint16_t)r;
}

__device__ __forceinline__ uint32_t pk2bf(float a, float b) {
    union { __hip_bfloat162 h; uint32_t u; } v;
    v.h = __float22bfloat162_rn(float2{a, b});
    return v.u;
}

__device__ __forceinline__ bf16x8 cvt8(const float* __restrict__ p) {
    f32x4 a = *(const f32x4*)p;
    f32x4 b = *(const f32x4*)(p + 4);
    bf16x8 r;
    r[0] = f2bf(a[0]); r[1] = f2bf(a[1]); r[2] = f2bf(a[2]); r[3] = f2bf(a[3]);
    r[4] = f2bf(b[0]); r[5] = f2bf(b[1]); r[6] = f2bf(b[2]); r[7] = f2bf(b[3]);
    return r;
}

// ---------------------------------------------------------------------------
// Kernel 0: one-time weight pack (fp32 -> bf16, frag-blocked).
// Blocks 0..511: Wo -> wo_f  [ntile=n/16][kseg=k/32][lane=((k%32)/8)*16+n%16][8]
// Blocks 512..514: Wq/Wk/Wv -> wqkv_f[i][seg=nt*2+kf][lane][8] with element
//   W[nt*16+(lane&15)][kf*32+(lane>>4)*8+j]  (B-frag for projection MFMA).
// ---------------------------------------------------------------------------
__global__ __launch_bounds__(256)
void wpack_kernel(const float* __restrict__ Wo, const float* __restrict__ Wq,
                  const float* __restrict__ Wk, const float* __restrict__ Wv,
                  short* __restrict__ wo_f, short* __restrict__ wqkv_f) {
    int b = blockIdx.x;
    if (b < 512) {
        int idx = b * 256 + threadIdx.x;        // 0..131071
        int nrow = idx >> 7;                    // 0..1023
        int k0 = (idx & 127) * 8;               // 0..1016
        bf16x8 v = cvt8(Wo + (size_t)nrow * 1024 + k0);
        int ntile = nrow >> 4, lcn = nrow & 15;
        int kseg = k0 >> 5, qd = (k0 >> 3) & 3;
        *(bf16x8*)(wo_f + ((size_t)(ntile * 32 + kseg) * 64 + qd * 16 + lcn) * 8) = v;
    } else {
        const float* W = (b == 512) ? Wq : (b == 513) ? Wk : Wv;
        short* dst = wqkv_f + (size_t)(b - 512) * 4096;
        for (int u = threadIdx.x; u < 512; u += 256) {
            int seg = u >> 6, ln = u & 63;
            int nt = seg >> 1, kf = seg & 1, lq = ln >> 4, lcn = ln & 15;
            bf16x8 v = cvt8(W + (nt * 16 + lcn) * 64 + kf * 32 + lq * 8);
            *(bf16x8*)(dst + u * 8) = v;
        }
    }
}

// ---------------------------------------------------------------------------
// Kernel 1: K/V projection -> frag-blocked workspaces.
// kf_ws[nh][kt][seg=t*2+kf][lane][8]: K[key=kt*64+t*16+(lane&15)][d=kf*32+(lane>>4)*8+j]
// vf_ws[nh][kt][seg=dt*2+kf][lane][8]: V[key=kt*64+kf*32+(lane>>4)*8+j][d=dt*16+(lane&15)]
// ---------------------------------------------------------------------------
__global__ __launch_bounds__(256)
void kvproj_kernel(const float* __restrict__ x, const short* __restrict__ wqkv_f,
                   short* __restrict__ kf_ws, short* __restrict__ vf_ws) {
    __shared__ alignas(16) short kbuf[128 * 72];   // X stage, then K[key][d]
    __shared__ alignas(16) short vbuf[64 * 136];   // V^T[d][key 0..127]
    int tid = threadIdx.x;
    int lt = blockIdx.x & 15, nh = blockIdx.x >> 4;
    int n = nh >> 4, h = nh & 15;
    int l0 = lt * 128, kt0 = lt * 2;
    int wv = tid >> 6, lane = tid & 63, quad = lane >> 4, lc = lane & 15;
    const short* wkf = wqkv_f + 4096 + lane * 8;   // Wk frags
    const short* wvf = wqkv_f + 8192 + lane * 8;   // Wv frags

    for (int u = tid; u < 1024; u += 256) {
        int r = u >> 3, c = (u & 7) * 8;
        *(bf16x8*)(kbuf + r * 72 + c) =
            cvt8(x + (size_t)(n * 2048 + l0 + r) * 1024 + h * 64 + c);
    }
    __syncthreads();

    bf16x8 xa[2][2];
    for (int mt = 0; mt < 2; ++mt)
        for (int kf = 0; kf < 2; ++kf)
            xa[mt][kf] = *(bf16x8*)(kbuf + (wv * 32 + mt * 16 + lc) * 72 + kf * 32 + quad * 8);

    f32x4 ka[2][4] = {}, va[2][4] = {};
    for (int nt = 0; nt < 4; ++nt)
        for (int kf = 0; kf < 2; ++kf) {
            bf16x8 wkb = *(const bf16x8*)(wkf + (nt * 2 + kf) * 512);
            bf16x8 wvb = *(const bf16x8*)(wvf + (nt * 2 + kf) * 512);
            for (int mt = 0; mt < 2; ++mt) {
                ka[mt][nt] = mfma16(xa[mt][kf], wkb, ka[mt][nt]);
                va[mt][nt] = mfma16(xa[mt][kf], wvb, va[mt][nt]);
            }
        }

    for (int mt = 0; mt < 2; ++mt) {
        int off = wv * 32 + mt * 16;  // key base within 128
        for (int nt = 0; nt < 4; ++nt) {
            short4v pv;
            for (int i = 0; i < 4; ++i) {
                kbuf[(off + quad * 4 + i) * 72 + nt * 16 + lc] = f2bf(ka[mt][nt][i]);
                pv[i] = f2bf(va[mt][nt][i]);
            }
            *(short4v*)(vbuf + (nt * 16 + lc) * 136 + off + quad * 4) = pv;
        }
    }
    __syncthreads();

    // coalesced frag-blocked stores (lane*16B contiguous)
    size_t base = (size_t)nh * 131072 + (size_t)kt0 * 4096;
    for (int u = tid; u < 1024; u += 256) {
        int tile = u >> 9, rem = u & 511, seg = rem >> 6, ln = u & 63;
        int t = seg >> 1, kf = seg & 1;
        int lq = ln >> 4, ll = ln & 15;
        bf16x8 kw = *(bf16x8*)(kbuf + (tile * 64 + t * 16 + ll) * 72 + kf * 32 + lq * 8);
        *(bf16x8*)(kf_ws + base + (size_t)tile * 4096 + seg * 512 + ln * 8) = kw;
        bf16x8 vw = *(bf16x8*)(vbuf + (t * 16 + ll) * 136 + tile * 64 + kf * 32 + lq * 8);
        *(bf16x8*)(vf_ws + base + (size_t)tile * 4096 + seg * 512 + ln * 8) = vw;
    }
}

// ---------------------------------------------------------------------------
// Kernel 2: fused Q-projection + flash attention, transposed-S formulation.
// grid: blockIdx = qt*64 + nh (b%8 == nh%8 -> same-nh blocks share an XCD).
// block = 256 = 4 waves x 32 q-rows (128-q tile), 16 qt -> grid 1024
// -> 4 blocks/CU co-resident (LDS 18 KB) for latency hiding.
// AO is written A-FRAG-BLOCKED for the out-GEMM.
// ---------------------------------------------------------------------------
__global__ __launch_bounds__(256)
void flash_kernel(const float* __restrict__ x, const short* __restrict__ wqkv_f,
                  const short* __restrict__ kf_ws, const short* __restrict__ vf_ws,
                  short* __restrict__ ao) {
    __shared__ alignas(16) short pbuf[128 * 72];  // 18 KB
    int tid = threadIdx.x;
    int nh = blockIdx.x & 63, qt = blockIdx.x >> 6;
    int n = nh >> 4, h = nh & 15;
    int q0 = qt * 128;
    int wv = tid >> 6, lane = tid & 63, quad = lane >> 4, lc = lane & 15;

    // ---- fused Q projection: stage X (128 rows), each wave projects its 32 ----
    for (int u = tid; u < 1024; u += 256) {
        int r = u >> 3, c = (u & 7) * 8;
        *(bf16x8*)(pbuf + r * 72 + c) =
            cvt8(x + (size_t)(n * 2048 + q0 + r) * 1024 + h * 64 + c);
    }
    __syncthreads();
    {
        const short* wqf = wqkv_f + lane * 8;
        bf16x8 xa[2][2];
        for (int mt = 0; mt < 2; ++mt)
            for (int kf = 0; kf < 2; ++kf)
                xa[mt][kf] = *(bf16x8*)(pbuf + (wv * 32 + mt * 16 + lc) * 72 +
                                        kf * 32 + quad * 8);
        f32x4 qacc[2][4] = {};
        for (int nt = 0; nt < 4; ++nt)
            for (int kf = 0; kf < 2; ++kf) {
                bf16x8 wb = *(const bf16x8*)(wqf + (nt * 2 + kf) * 512);
                for (int mt = 0; mt < 2; ++mt)
                    qacc[mt][nt] = mfma16(xa[mt][kf], wb, qacc[mt][nt]);
            }
        const float QS = 0.04508422002778011f;  // log2(e) / sqrt(1024)
        for (int mt = 0; mt < 2; ++mt)
            for (int nt = 0; nt < 4; ++nt)
                for (int i = 0; i < 4; ++i)
                    pbuf[(wv * 32 + mt * 16 + quad * 4 + i) * 72 + nt * 16 + lc] =
                        f2bf(qacc[mt][nt][i] * QS);
    }
    bf16x8 qa[2][2];
    for (int mt = 0; mt < 2; ++mt)
        for (int kf = 0; kf < 2; ++kf)
            qa[mt][kf] = *(bf16x8*)(pbuf + (wv * 32 + mt * 16 + lc) * 72 +
                                    kf * 32 + quad * 8);

    f32x4 o[2][4] = {};        // o[q2][dt]: O^T[d=dt*16+quad*4+i][q=q2*16+lc]
    float lsum[2] = {0.f, 0.f};
    const short* kbase = kf_ws + (size_t)nh * 131072 + lane * 8;
    const short* vbase = vf_ws + (size_t)nh * 131072 + lane * 8;

    for (int kt = 0; kt < 32; ++kt) {
        const short* kp = kbase + (size_t)kt * 4096;
        const short* vp = vbase + (size_t)kt * 4096;
        bf16x8 kA[4][2];
#pragma unroll
        for (int t = 0; t < 4; ++t)
            for (int kf = 0; kf < 2; ++kf)
                kA[t][kf] = *(const bf16x8*)(kp + (t * 2 + kf) * 512);
        f32x4 s[2][4] = {};
#pragma unroll
        for (int t = 0; t < 4; ++t)
            for (int q2 = 0; q2 < 2; ++q2) {
                s[q2][t] = mfma16(kA[t][0], qa[q2][0], s[q2][t]);
                s[q2][t] = mfma16(kA[t][1], qa[q2][1], s[q2][t]);
            }
        bf16x8 vA[4][2];
#pragma unroll
        for (int dt = 0; dt < 4; ++dt)
            for (int kf = 0; kf < 2; ++kf)
                vA[dt][kf] = *(const bf16x8*)(vp + (dt * 2 + kf) * 512);
#pragma unroll
        for (int q2 = 0; q2 < 2; ++q2) {
            int prow = (wv * 32 + q2 * 16 + lc) * 72;
            float ts = 0.f;
#pragma unroll
            for (int t = 0; t < 4; ++t) {
                float p0 = __builtin_amdgcn_exp2f(s[q2][t][0]);
                float p1 = __builtin_amdgcn_exp2f(s[q2][t][1]);
                float p2 = __builtin_amdgcn_exp2f(s[q2][t][2]);
                float p3 = __builtin_amdgcn_exp2f(s[q2][t][3]);
                ts += (p0 + p1) + (p2 + p3);
                uint2v w = {pk2bf(p0, p1), pk2bf(p2, p3)};
                *(uint2v*)(pbuf + prow + t * 16 + quad * 4) = w;
            }
            lsum[q2] += ts;
        }
#pragma unroll
        for (int q2 = 0; q2 < 2; ++q2)
            for (int kf = 0; kf < 2; ++kf) {
                bf16x8 pB = *(bf16x8*)(pbuf + (wv * 32 + q2 * 16 + lc) * 72 +
                                       kf * 32 + quad * 8);
                for (int dt = 0; dt < 4; ++dt)
                    o[q2][dt] = mfma16(vA[dt][kf], pB, o[q2][dt]);
            }
    }

    // epilogue: reduce lsum across quads, normalize, store AO frag-blocked
    for (int q2 = 0; q2 < 2; ++q2) {
        float t = lsum[q2];
        t += __shfl_xor(t, 16, 64);
        t += __shfl_xor(t, 32, 64);
        float inv = 1.f / t;
        int mtile = (n * 2048 + q0) / 16 + wv * 2 + q2;  // row r%16 = lc
        for (int dt = 0; dt < 4; ++dt) {
            // k = h*64 + dt*16 + quad*4 + i
            int kseg = h * 2 + (dt >> 1);
            int qd8 = ((dt & 1) * 4 + quad) >> 1;
            short4v pk;
            for (int i = 0; i < 4; ++i) pk[i] = f2bf(o[q2][dt][i] * inv);
            *(short4v*)(ao + (size_t)(mtile * 32 + kseg) * 512 +
                        (qd8 * 16 + lc) * 8 + (quad & 1) * 4) = pk;
        }
    }
}

// ---------------------------------------------------------------------------
// Kernel 3: out = AO @ Wo^T + bo.  M=8192, N=1024, K=1024.
// Pure register-streaming GEMM: A-frags from afb, B-frags from wo_f, no LDS,
// no barriers.  grid: blockIdx = bn*64 + bm -> same-A (bm) blocks share XCD.
// ---------------------------------------------------------------------------
__global__ __launch_bounds__(256)
void outgemm_kernel(const short* __restrict__ afb, const short* __restrict__ wfb,
                    const float* __restrict__ bo, float* __restrict__ out) {
    int tid = threadIdx.x;
    int bm = blockIdx.x & 63, bn = blockIdx.x >> 6;
    int m0 = bm * 128, n0 = bn * 128;
    int wv = tid >> 6, lane = tid & 63, quad = lane >> 4, lc = lane & 15;
    int wr = wv >> 1, wc = wv & 1;
    int mtb = bm * 8 + wr * 4;   // A row-tile base (16-row tiles)
    int ntb = bn * 8 + wc * 4;   // B col-tile base

    const short* ab = afb + lane * 8;
    const short* bb = wfb + lane * 8;

    f32x4 acc[4][4] = {};
    for (int kt = 0; kt < 32; ++kt) {
        bf16x8 af[4], bfr[4];
#pragma unroll
        for (int mt = 0; mt < 4; ++mt)
            af[mt] = *(const bf16x8*)(ab + ((size_t)(mtb + mt) * 32 + kt) * 512);
#pragma unroll
        for (int nt = 0; nt < 4; ++nt)
            bfr[nt] = *(const bf16x8*)(bb + ((size_t)(ntb + nt) * 32 + kt) * 512);
#pragma unroll
        for (int mt = 0; mt < 4; ++mt)
            for (int nt = 0; nt < 4; ++nt)
                acc[mt][nt] = mfma16(af[mt], bfr[nt], acc[mt][nt]);
    }
    for (int nt = 0; nt < 4; ++nt) {
        float bv = bo[n0 + wc * 64 + nt * 16 + lc];
        for (int mt = 0; mt < 4; ++mt)
            for (int i = 0; i < 4; ++i) {
                int m = m0 + wr * 64 + mt * 16 + quad * 4 + i;
                int nn = n0 + wc * 64 + nt * 16 + lc;
                out[(size_t)m * 1024 + nn] = acc[mt][nt][i] + bv;
            }
    }
}

extern "C" void kernel_launch(void* const* d_in, const int* in_sizes, int n_in,
                              void* d_out, int out_size, void* d_ws, size_t ws_size,
                              hipStream_t stream) {
    const float* x  = (const float*)d_in[0];
    const float* Wq = (const float*)d_in[1];
    const float* Wk = (const float*)d_in[2];
    const float* Wv = (const float*)d_in[3];
    const float* Wo = (const float*)d_in[4];
    const float* bo = (const float*)d_in[5];
    float* out = (float*)d_out;

    short* kf_ws   = (short*)d_ws;         // frag-blocked K (16 MB)
    short* vf_ws   = kf_ws + 8388608;      // frag-blocked V^T (16 MB)
    short* ao_ws   = vf_ws + 8388608;      // frag-blocked AO (16 MB)
    short* wo_f    = ao_ws + 8388608;      // Wo frags (2 MB)
    short* wqkv_f  = wo_f + 1048576;       // Wq/Wk/Wv frags (24 KB)

    wpack_kernel<<<dim3(515), dim3(256), 0, stream>>>(Wo, Wq, Wk, Wv, wo_f, wqkv_f);
    kvproj_kernel<<<dim3(1024), dim3(256), 0, stream>>>(x, wqkv_f, kf_ws, vf_ws);
    flash_kernel<<<dim3(1024), dim3(256), 0, stream>>>(x, wqkv_f, kf_ws, vf_ws, ao_ws);
    outgemm_kernel<<<dim3(512), dim3(256), 0, stream>>>(ao_ws, wo_f, bo, out);
}